// Round 10
// baseline (416.735 us; speedup 1.0000x reference)
//
#include <hip/hip_runtime.h>

#define TB 512
#define NIMG 512
#define HW 28
#define NPIX 784
#define TT 8
#define NFC 100
#define NOUT 10
#define MAGIC 0x5C5C5C5Cu

// workspace: wT [3136][100] floats, vfcb [512][2][8][100] floats, u32 ctrl[]:
//   ctrl[0..97]   = transpose-done flags (MAGIC when slice written)
//   ctrl[98..129] = fr_g[32] (float)
//   ctrl[130]     = done2 counter (winners)
//   ctrl[131]     = fr_ready flag
//   ctrl[132..643]= pair[512] counters
#define WT_FLOATS 313600
#define VFCB_FLOATS (NIMG * 2 * TT * NFC)
#define GLB_ADD(p, v) __hip_atomic_fetch_add((p), (v), __ATOMIC_RELAXED, __HIP_MEMORY_SCOPE_AGENT)

typedef float f4 __attribute__((ext_vector_type(4)));

// ---------------------------------------------------------------------------
// Two blocks (512 thr) per image: half=0 rows 0..13, half=1 rows 14..27.
// NOTE round-9 lesson: __launch_bounds__(512,8) forced VGPR=32 and crippled
// codegen (VALUBusy 43%->18%, 2.5x slower). Bounds (512,4) let round 7's
// code compile at 40 VGPR, which is ALREADY under the 64-VGPR line for
// 4 blocks/CU — hardware occupancy follows actual VGPR use, not the bound.
__global__ __launch_bounds__(TB, 4)
void snn_main(const float* __restrict__ xg, const float* __restrict__ w_sconv,
              const float* __restrict__ w_conv, const float* __restrict__ w_fc1,
              const float* __restrict__ w_fc2, float* __restrict__ wT,
              float* __restrict__ vfcb, float* __restrict__ out,
              unsigned int* __restrict__ ctrl)
{
    // overlaid span:
    //   [wc 11520][xst|t2n 3136][wsc 576][mask_t 6720][rowOr 256] = 22208
    //   prefixLDS (25600) overlays the whole span after the pool phase.
    __shared__ unsigned char span[25600] __attribute__((aligned(16)));
    __shared__ unsigned short slist[1568];      // windows sorted by t (global u)
    __shared__ unsigned char tqA[1568];         // pooled first-spike t; later t3L
    __shared__ int bcnt[9], bofs[9], bput[8];
    __shared__ int hist[32];                    // [layer*8 + t]
    __shared__ int winflag, lastflag;

    float* wc = (float*)span;                                   // [r*20 + co]
    float* xst = (float*)(span + 11520);                        // image (phase A)
    unsigned int* t2n = (unsigned int*)(span + 11520);          // overlays xst
    float* wsc = (float*)(span + 14656);
    unsigned short* mask_t = (unsigned short*)(span + 15232);   // [t*420 + rl*28+x]
    unsigned int* mask32 = (unsigned int*)(span + 15232);
    unsigned short* rowOr = (unsigned short*)(span + 21952);    // [t*16 + rl]
    float* prefixLDS = (float*)span;                            // [w][t][neuron]

    unsigned int* tflags = ctrl;
    float* fr_g = (float*)(ctrl + 98);
    unsigned int* done2 = ctrl + 130;
    unsigned int* fr_ready = ctrl + 131;
    unsigned int* pair = ctrl + 132;

    const int tid = threadIdx.x;
    const int b = blockIdx.x >> 1;
    const int half = blockIdx.x & 1;
    const int mrow0 = half ? 13 : 0;            // mask strip = global rows mrow0..mrow0+14

    // ---- cooperative transpose (blocks 0..97) + block-0 accumulator zeroing
    if (blockIdx.x < 98) {
        const int c0 = blockIdx.x * 32;
        for (int idx = tid; idx < 3200; idx += TB) {
            int c = idx / 100, r = idx - 100 * c;
            wT[(c0 + c) * 100 + r] = w_fc1[r * 3136 + c0 + c];
        }
    }
    if (blockIdx.x == 0) {                      // fr_g + done2 + fr_ready + pair[512]
        for (int i = 98 + tid; i < 644; i += TB) ctrl[i] = 0u;
    }

    // ---- stage
    for (int i = tid; i < NPIX; i += TB) xst[i] = xg[b * NPIX + i];
    for (int i = tid; i < 144; i += TB) wsc[i] = w_sconv[i];
    for (int i = tid; i < 2304; i += TB) {
        int c = i & 15, r = i >> 4;             // r = ci*9 + k, c = co
        wc[r * 20 + c] = w_conv[c * 144 + r];
    }
    for (int i = tid; i < 1680; i += TB) mask32[i] = 0u;        // 8*420 u16
    if (tid < 32) hist[tid] = 0;
    if (tid < 9) bcnt[tid] = 0;
    if (blockIdx.x < 98) __threadfence();
    __syncthreads();
    if (tid == 0) {
        if (blockIdx.x < 98)
            __hip_atomic_store(&tflags[blockIdx.x], MAGIC, __ATOMIC_RELEASE,
                               __HIP_MEMORY_SCOPE_AGENT);
        if (blockIdx.x == 0)
            __hip_atomic_store(fr_ready, MAGIC, __ATOMIC_RELEASE,
                               __HIP_MEMORY_SCOPE_AGENT);
    }

    // ---- phase A: closed-form t1 over the 15-row halo strip -> mask bits
    unsigned int pca = 0, pcb = 0;
#pragma unroll 1
    for (int e = 0; e < 14; e++) {
        int g = e * TB + tid;
        if (g < 6720) {                         // 15 rows * 28 * 16
            int ci = g & 15, p = g >> 4;        // p = rl*28 + x
            int rl = p / HW, xx = p - rl * HW;
            int gy = mrow0 + rl;
            float acc = 0.f;
#pragma unroll
            for (int ky = 0; ky < 3; ky++) {
                int ys = gy + ky - 1;
                if (ys < 0 || ys >= HW) continue;
#pragma unroll
                for (int kx = 0; kx < 3; kx++) {
                    int xsrc = xx + kx - 1;
                    if (xsrc < 0 || xsrc >= HW) continue;
                    acc = fmaf(wsc[ci * 9 + ky * 3 + kx], xst[ys * HW + xsrc], acc);
                }
            }
            int t1 = 8; float v = 0.f;
#pragma unroll
            for (int t = 0; t < TT; t++) {      // exact reference add order
                v += acc;
                if (t1 == 8 && v >= 1.0f) t1 = t;
            }
            if (t1 < 8) {
                int lin = t1 * 420 + p;
                atomicOr(&mask32[lin >> 1], (1u << ci) << ((lin & 1) * 16));
                bool owned = half ? (rl >= 1) : (rl < 14);   // count each neuron once
                if (owned) {
                    if (t1 < 4) pca += 1u << (t1 * 8); else pcb += 1u << ((t1 - 4) * 8);
                }
            }
        }
    }
#pragma unroll
    for (int t = 0; t < TT; t++) {
        unsigned int c = ((t < 4 ? (pca >> (t * 8)) : (pcb >> ((t - 4) * 8))) & 255u);
        if (c) atomicAdd(&hist[t], (int)c);
    }
    __syncthreads();

    // ---- row-union skip table
    for (int i = tid; i < TT * 15; i += TB) {   // i = t*15 + rl
        int t = i / 15, rl = i - t * 15;
        const unsigned short* mr = mask_t + t * 420 + rl * HW;
        unsigned int o = 0;
#pragma unroll
        for (int x = 0; x < HW; x++) o |= mr[x];
        rowOr[t * 16 + rl] = (unsigned short)o;
    }
    __syncthreads();

    // ---- gather: 392 positions, v2[16] in packed f4 regs, LDS masks
    unsigned int pc2a = 0, pc2b = 0;
    if (tid < 392) {
        const int py_l = tid / HW, px = tid - py_l * HW;
        const int cr = py_l + (half ? 1 : 0);   // center mask row
        f4 vv0 = {0.f, 0.f, 0.f, 0.f}, vv1 = vv0, vv2 = vv0, vv3 = vv0;
        unsigned int done = 0;
        unsigned int t2lo = 0x88888888u, t2hi = 0x88888888u;
#pragma unroll 1
        for (int t = 0; t < TT; t++) {
            const unsigned short* ro = rowOr + t * 16;
            unsigned int un = ro[cr];
            if (cr > 0) un |= ro[cr - 1];
            if (cr < 14) un |= ro[cr + 1];
            if (!un) continue;                  // no adds at t -> no new crossing
            const unsigned short* mt = mask_t + t * 420;
#pragma unroll
            for (int k = 0; k < 9; k++) {
                int mr = cr + k / 3 - 1, qx = px + k % 3 - 1;
                if ((unsigned)mr >= 15u || (unsigned)qx >= HW) continue;
                unsigned int m = mt[mr * HW + qx];
                while (m) {
                    int ci = __builtin_ctz(m); m &= m - 1;
                    const f4* wrow = (const f4*)&wc[(ci * 9 + k) * 20];
                    vv0 += wrow[0]; vv1 += wrow[1];
                    vv2 += wrow[2]; vv3 += wrow[3];
                }
            }
            unsigned int fired = 0;
#pragma unroll
            for (int c = 0; c < 16; c++) {
                float val = (c < 4) ? vv0[c & 3] : (c < 8) ? vv1[c & 3]
                          : (c < 12) ? vv2[c & 3] : vv3[c & 3];
                fired |= (val >= 1.0f) ? (1u << c) : 0u;
            }
            unsigned int newf = fired & ~done;
            done |= newf;
            if (newf) {
                int cnt = __builtin_popcount(newf);
                if (t < 4) pc2a += (unsigned)cnt << (t * 8);
                else       pc2b += (unsigned)cnt << ((t - 4) * 8);
                while (newf) {
                    int c = __builtin_ctz(newf); newf &= newf - 1;
                    if (c < 8) t2lo = (t2lo & ~(15u << (4 * c))) | ((unsigned)t << (4 * c));
                    else       t2hi = (t2hi & ~(15u << (4 * (c - 8)))) | ((unsigned)t << (4 * (c - 8)));
                }
            }
            if (done == 0xffffu) break;
        }
        t2n[tid * 2] = t2lo;                    // overlays dead xst
        t2n[tid * 2 + 1] = t2hi;
    }
#pragma unroll
    for (int t = 0; t < TT; t++) {
        unsigned int c = ((t < 4 ? (pc2a >> (t * 8)) : (pc2b >> ((t - 4) * 8))) & 255u);
        if (c) atomicAdd(&hist[8 + t], (int)c);
    }
    __syncthreads();

    // ---- first-spike pool (7 window rows) + bucket histogram
    for (int u = tid; u < 1568; u += TB) {      // u = c*98 + wy_l*14 + wx
        int c = u / 98, rem = u - c * 98;
        int wy = rem / 14, wx = rem - wy * 14;
        int p0 = wy * 56 + wx * 2;              // gather-local pos
        int wsel = c >> 3, sh = (c & 7) * 4;
        int m0 = (t2n[p0 * 2 + wsel] >> sh) & 15;
        int m1 = (t2n[(p0 + 1) * 2 + wsel] >> sh) & 15;
        int m2 = (t2n[(p0 + HW) * 2 + wsel] >> sh) & 15;
        int m3 = (t2n[(p0 + HW + 1) * 2 + wsel] >> sh) & 15;
        int tqv = min(min(m0, m1), min(m2, m3));
        tqA[u] = (unsigned char)tqv;
        if (tqv < 8) atomicAdd(&bcnt[tqv], 1);
    }
    __syncthreads();
    if (tid == 0) {
        int s = 0;
#pragma unroll
        for (int t = 0; t < TT; t++) { bofs[t] = s; s += bcnt[t]; }
        bofs[8] = s;
    }
    __syncthreads();
    if (tid < 8) bput[tid] = bofs[tid];
    __syncthreads();
    for (int u = tid; u < 1568; u += TB) {
        int tqv = tqA[u];
        if (tqv < 8) {
            int j = atomicAdd(&bput[tqv], 1);
            int c = u / 98, rem = u - c * 98;
            int wy = rem / 14, wx = rem - wy * 14;
            slist[j] = (unsigned short)(c * 196 + (half * 7 + wy) * 14 + wx);
        }
    }

    // ---- wait for wT slices (long since done)
    if (tid < 98) {
        while (__hip_atomic_load(&tflags[tid], __ATOMIC_ACQUIRE,
                                 __HIP_MEMORY_SCOPE_AGENT) != MAGIC)
            __builtin_amdgcn_s_sleep(2);
    }
    __syncthreads();                            // also: wc/mask/t2n dead -> prefix reuse

    // ---- FC1 sorted-prefix scan: 8 single-wave streams, unroll-4 loads
    {
        const int lane = tid & 63;
        const int w = tid >> 6;
        const float* wA = wT + lane;
        const float* wB = wT + 64 + lane;
        float acc0 = 0.f, acc1 = 0.f;
#pragma unroll 1
        for (int t = 0; t < TT; t++) {
            const int lo = bofs[t];
            const int n = bofs[t + 1] - lo;
            int j = w;
            for (; j + 24 < n; j += 32) {
                int u0 = (int)slist[lo + j] * 100;
                int u1 = (int)slist[lo + j + 8] * 100;
                int u2 = (int)slist[lo + j + 16] * 100;
                int u3 = (int)slist[lo + j + 24] * 100;
                float a0 = wA[u0], a1 = wA[u1], a2 = wA[u2], a3 = wA[u3];
                if (lane < 36) {
                    float b0 = wB[u0], b1 = wB[u1], b2 = wB[u2], b3 = wB[u3];
                    acc1 += b0; acc1 += b1; acc1 += b2; acc1 += b3;
                }
                acc0 += a0; acc0 += a1; acc0 += a2; acc0 += a3;
            }
            for (; j < n; j += 8) {
                int u0 = (int)slist[lo + j] * 100;
                acc0 += wA[u0];
                if (lane < 36) acc1 += wB[u0];
            }
            prefixLDS[(w * TT + t) * NFC + lane] = acc0;
            if (lane < 36) prefixLDS[(w * TT + t) * NFC + 64 + lane] = acc1;
        }
    }
    __syncthreads();

    // ---- store half-prefix to private global region (no zero/atomics needed)
    if (tid < NFC) {
#pragma unroll
        for (int t = 0; t < TT; t++) {
            float s = 0.f;
#pragma unroll
            for (int w = 0; w < 8; w++) s += prefixLDS[(w * TT + t) * NFC + tid];
            vfcb[(((size_t)b * 2 + half) * TT + t) * NFC + tid] = s;
        }
    }

    // ---- fr_ready gate, flush hist1/2, pair election
    if (tid == 0) {
        while (__hip_atomic_load(fr_ready, __ATOMIC_ACQUIRE,
                                 __HIP_MEMORY_SCOPE_AGENT) != MAGIC)
            __builtin_amdgcn_s_sleep(2);
    }
    __syncthreads();
    if (tid < 16) {
        int h = hist[tid];
        if (h) GLB_ADD(&fr_g[(tid & 7) * 4 + (tid >> 3)], (float)h);
    }
    __threadfence();
    __syncthreads();
    if (tid == 0) {
        unsigned int old = __hip_atomic_fetch_add(&pair[b], 1u, __ATOMIC_ACQ_REL,
                                                  __HIP_MEMORY_SCOPE_AGENT);
        winflag = (old == 1u);
    }
    __syncthreads();
    if (!winflag) return;                       // loser half exits

    // ---- winner tail: t3 from both halves' prefixes
    if (tid < NFC) {
        int t3 = 8;
#pragma unroll
        for (int t = 0; t < TT; t++) {
            float v = __hip_atomic_load(&vfcb[(((size_t)b * 2 + 0) * TT + t) * NFC + tid],
                                        __ATOMIC_RELAXED, __HIP_MEMORY_SCOPE_AGENT)
                    + __hip_atomic_load(&vfcb[(((size_t)b * 2 + 1) * TT + t) * NFC + tid],
                                        __ATOMIC_RELAXED, __HIP_MEMORY_SCOPE_AGENT);
            if (t3 == 8 && v >= 1.0f) t3 = t;
        }
        tqA[tid] = (unsigned char)t3;
        if (t3 < 8) atomicAdd(&hist[16 + t3], 1);
    }
    __syncthreads();

    // ---- FC2 buckets + readout IF sim + latency score
    if (tid < NOUT) {
        float acc8[TT] = {0.f, 0.f, 0.f, 0.f, 0.f, 0.f, 0.f, 0.f};
        for (int i = 0; i < NFC; i++) {
            float w = w_fc2[tid * NFC + i];
            int tv = tqA[i];
#pragma unroll
            for (int k = 0; k < TT; k++) acc8[k] += (tv == k) ? w : 0.f;
        }
        float vout = 0.f; int cnt = 0; float lat = 0.f;
#pragma unroll
        for (int t = 0; t < TT; t++) {
            vout += acc8[t];
            if (vout >= 1.0f) { vout = 0.f; cnt++; atomicAdd(&hist[24 + t], 1); }
            if (cnt >= 1) lat += 1.f;
        }
        out[b * NOUT + tid] = lat * 0.125f;
    }
    __syncthreads();
    if (tid >= 16 && tid < 32) {
        int h = hist[tid];
        if (h) GLB_ADD(&fr_g[(tid & 7) * 4 + (tid >> 3)], (float)h);
    }
    __threadfence();
    __syncthreads();

    // ---- last winner computes reg_loss
    if (tid == 0) {
        unsigned int old = __hip_atomic_fetch_add(done2, 1u, __ATOMIC_ACQ_REL,
                                                  __HIP_MEMORY_SCOPE_AGENT);
        lastflag = (old == (unsigned)(NIMG - 1));
    }
    __syncthreads();
    if (lastflag && tid == 0) {
        const float inv0 = 1.f / 6422528.f;     // B*16*28*28
        const float inv2 = 1.f / 51200.f;       // B*100
        const float inv3 = 1.f / 5120.f;        // B*10
        const float invs[4] = { inv0, inv0, inv2, inv3 };
        float reg = 0.f;
        for (int l = 0; l < 4; l++) {
            float mx = -INFINITY;
            for (int t = 0; t < TT; t++) {
                float v = __hip_atomic_load(&fr_g[t * 4 + l], __ATOMIC_RELAXED,
                                            __HIP_MEMORY_SCOPE_AGENT);
                mx = fmaxf(mx, v * invs[l]);
            }
            reg += mx;
        }
        out[NIMG * NOUT] = reg;
    }
}

// ---------------------------------------------------------------------------
extern "C" void kernel_launch(void* const* d_in, const int* in_sizes, int n_in,
                              void* d_out, int out_size, void* d_ws, size_t ws_size,
                              hipStream_t stream) {
    const float* x       = (const float*)d_in[0];
    const float* w_sconv = (const float*)d_in[1];
    const float* w_conv  = (const float*)d_in[2];
    const float* w_fc1   = (const float*)d_in[3];
    const float* w_fc2   = (const float*)d_in[4];
    float* out = (float*)d_out;

    float* wT          = (float*)d_ws;
    float* vfcb        = wT + WT_FLOATS;
    unsigned int* ctrl = (unsigned int*)(vfcb + VFCB_FLOATS);

    snn_main<<<NIMG * 2, TB, 0, stream>>>(x, w_sconv, w_conv, w_fc1, w_fc2,
                                          wT, vfcb, out, ctrl);
}

// Round 12
// 207.677 us; speedup vs baseline: 2.0067x; 2.0067x over previous
//
#include <hip/hip_runtime.h>

#define TB 512
#define NIMG 512
#define HW 28
#define NPIX 784
#define TT 8
#define NFC 100
#define NOUT 10
#define MAGIC 0x5C5C5C5Cu

// workspace: wT [3136][100] floats, vfcb [512][2][8][100] floats, u32 ctrl[]:
//   ctrl[0..97]   = transpose-done flags, ctrl[98..129] = fr_g[32] (float)
//   ctrl[130]     = done2 counter (snn_d), ctrl[131] = fr_ready flag
#define WT_FLOATS 313600
#define VFCB_FLOATS (NIMG * 2 * TT * NFC)
#define GLB_ADD(p, v) __hip_atomic_fetch_add((p), (v), __ATOMIC_RELAXED, __HIP_MEMORY_SCOPE_AGENT)

typedef float f4 __attribute__((ext_vector_type(4)));

// ---------------------------------------------------------------------------
// Two blocks (512 thr) per image, split by OUTPUT channel: half h covers
// co = h*8 .. h*8+7. Phase A (all-16-ci masks) duplicated per pair; gather
// keeps R7's own-loop/skip-table shape with an 8-float accumulator.
// vfcb[b][half][t] holds the CUMULATIVE prefix at time t (snn_d must NOT
// re-accumulate across t — that was round 11's bug).
__global__ __launch_bounds__(TB, 4)
void snn_main(const float* __restrict__ xg, const float* __restrict__ w_sconv,
              const float* __restrict__ w_conv, const float* __restrict__ w_fc1,
              const float* __restrict__ w_fc2, float* __restrict__ wT,
              float* __restrict__ vfcb, float* __restrict__ out,
              unsigned int* __restrict__ ctrl)
{
    // overlaid span:
    //   [wc 6912][xst|t2n 3136][wsc 576][mask_t 12544][rowOr 512] = 23680
    //   prefixLDS (25600) overlays everything after the pool phase.
    __shared__ unsigned char span[25600] __attribute__((aligned(16)));
    __shared__ unsigned short slist[1568];      // fired windows (global u), sorted by t
    __shared__ unsigned char tqA[1568];         // pooled first-spike t
    __shared__ int bcnt[9], bofs[9], bput[8];
    __shared__ int hist[32];                    // [layer*8 + t]

    float* wc = (float*)span;                                   // [r*12 + c], 8 co
    float* xst = (float*)(span + 6912);                         // image (phase A)
    unsigned int* t2n = (unsigned int*)(span + 6912);           // [pos]: 8co x 4b t2
    float* wsc = (float*)(span + 10048);
    unsigned short* mask_t = (unsigned short*)(span + 10624);   // [t*784 + pos]
    unsigned int* mask32 = (unsigned int*)(span + 10624);
    unsigned short* rowOr = (unsigned short*)(span + 23168);    // [t*32 + y]
    float* prefixLDS = (float*)span;                            // [w][t][neuron]

    unsigned int* tflags = ctrl;
    float* fr_g = (float*)(ctrl + 98);
    unsigned int* fr_ready = ctrl + 131;

    const int tid = threadIdx.x;
    const int b = blockIdx.x >> 1;
    const int half = blockIdx.x & 1;
    const int co0 = half * 8;

    // ---- cooperative transpose (blocks 0..97) + block-0 accumulator zeroing
    if (blockIdx.x < 98) {
        const int c0 = blockIdx.x * 32;
        for (int idx = tid; idx < 3200; idx += TB) {
            int c = idx / 100, r = idx - 100 * c;
            wT[(c0 + c) * 100 + r] = w_fc1[r * 3136 + c0 + c];
        }
    }
    if (blockIdx.x == 0) {                      // fr_g + done2 + fr_ready
        for (int i = 98 + tid; i < 132; i += TB) ctrl[i] = 0u;
    }

    // ---- stage
    for (int i = tid; i < NPIX; i += TB) xst[i] = xg[b * NPIX + i];
    for (int i = tid; i < 144; i += TB) wsc[i] = w_sconv[i];
    for (int i = tid; i < 1152; i += TB) {
        int c = i & 7, r = i >> 3;              // r = ci*9 + k, c = local co
        wc[r * 12 + c] = w_conv[(co0 + c) * 144 + r];
    }
    for (int i = tid; i < 3136; i += TB) mask32[i] = 0u;        // 8*784 u16
    if (tid < 32) hist[tid] = 0;
    if (tid < 9) bcnt[tid] = 0;
    if (blockIdx.x < 98) __threadfence();
    __syncthreads();
    if (tid == 0) {
        if (blockIdx.x < 98)
            __hip_atomic_store(&tflags[blockIdx.x], MAGIC, __ATOMIC_RELEASE,
                               __HIP_MEMORY_SCOPE_AGENT);
        if (blockIdx.x == 0)
            __hip_atomic_store(fr_ready, MAGIC, __ATOMIC_RELEASE,
                               __HIP_MEMORY_SCOPE_AGENT);
    }

    // ---- phase A: xs conv + closed-form t1 -> mask bits (all 16 ci)
    unsigned int pca = 0, pcb = 0;
#pragma unroll 1
    for (int e = 0; e < 25; e++) {
        int g = e * TB + tid;
        if (g < 12544) {
            int ci = g & 15, pos = g >> 4;
            int yy = pos / HW, xx = pos % HW;
            float acc = 0.f;
#pragma unroll
            for (int ky = 0; ky < 3; ky++) {
                int ys = yy + ky - 1;
                if (ys < 0 || ys >= HW) continue;
#pragma unroll
                for (int kx = 0; kx < 3; kx++) {
                    int xsrc = xx + kx - 1;
                    if (xsrc < 0 || xsrc >= HW) continue;
                    acc = fmaf(wsc[ci * 9 + ky * 3 + kx], xst[ys * HW + xsrc], acc);
                }
            }
            int t1 = 8; float v = 0.f;
#pragma unroll
            for (int t = 0; t < TT; t++) {      // exact reference add order
                v += acc;
                if (t1 == 8 && v >= 1.0f) t1 = t;
            }
            if (t1 < 8) {
                int lin = t1 * NPIX + pos;
                atomicOr(&mask32[lin >> 1], (1u << ci) << ((lin & 1) * 16));
                if (t1 < 4) pca += 1u << (t1 * 8); else pcb += 1u << ((t1 - 4) * 8);
            }
        }
    }
    if (half == 0) {                            // count layer-1 spikes once per image
#pragma unroll
        for (int t = 0; t < TT; t++) {
            unsigned int c = ((t < 4 ? (pca >> (t * 8)) : (pcb >> ((t - 4) * 8))) & 255u);
            if (c) atomicAdd(&hist[t], (int)c);
        }
    }
    __syncthreads();

    // ---- row-union skip table
    for (int i = tid; i < TT * HW; i += TB) {   // i = t*28 + y
        int t = i / HW, y = i - t * HW;
        const unsigned short* mr = mask_t + t * NPIX + y * HW;
        unsigned int o = 0;
#pragma unroll
        for (int x = 0; x < HW; x++) o |= mr[x];
        rowOr[t * 32 + y] = (unsigned short)o;
    }
    __syncthreads();

    // ---- gather: own-loop over 784 positions, v2[8] in packed f4 regs
    unsigned int pc2a = 0, pc2b = 0;
#pragma unroll 1
    for (int own = 0; own < 2; own++) {
        int pos = own * TB + tid;
        if (pos < NPIX) {
            int py = pos / HW, px = pos - py * HW;
            f4 vv0 = {0.f, 0.f, 0.f, 0.f}, vv1 = vv0;
            unsigned int done = 0;
            unsigned int t2p = 0x88888888u;     // 8 co x 4-bit, 8 = never
#pragma unroll 1
            for (int t = 0; t < TT; t++) {
                const unsigned short* ro = rowOr + t * 32;
                unsigned int un = ro[py];
                if (py > 0) un |= ro[py - 1];
                if (py < HW - 1) un |= ro[py + 1];
                if (!un) continue;              // no adds at t -> no new crossing
                const unsigned short* mt = mask_t + t * NPIX;
#pragma unroll
                for (int k = 0; k < 9; k++) {
                    int qy = py + k / 3 - 1, qx = px + k % 3 - 1;
                    if ((unsigned)qy >= HW || (unsigned)qx >= HW) continue;
                    unsigned int m = mt[qy * HW + qx];
                    while (m) {
                        int ci = __builtin_ctz(m); m &= m - 1;
                        const f4* wrow = (const f4*)&wc[(ci * 9 + k) * 12];
                        vv0 += wrow[0]; vv1 += wrow[1];
                    }
                }
                unsigned int fired = 0;
#pragma unroll
                for (int c = 0; c < 8; c++) {
                    float val = (c < 4) ? vv0[c & 3] : vv1[c & 3];
                    fired |= (val >= 1.0f) ? (1u << c) : 0u;
                }
                unsigned int newf = fired & ~done;
                done |= newf;
                if (newf) {
                    int cnt = __builtin_popcount(newf);
                    if (t < 4) pc2a += (unsigned)cnt << (t * 8);
                    else       pc2b += (unsigned)cnt << ((t - 4) * 8);
                    while (newf) {
                        int c = __builtin_ctz(newf); newf &= newf - 1;
                        t2p = (t2p & ~(15u << (4 * c))) | ((unsigned)t << (4 * c));
                    }
                }
                if (done == 0xffu) break;       // all 8 co fired
            }
            t2n[pos] = t2p;                     // overlays dead xst
        }
    }
#pragma unroll
    for (int t = 0; t < TT; t++) {
        unsigned int c = ((t < 4 ? (pc2a >> (t * 8)) : (pc2b >> ((t - 4) * 8))) & 255u);
        if (c) atomicAdd(&hist[8 + t], (int)c);
    }
    __syncthreads();

    // ---- first-spike pool + bucket histogram (8 local co x 196 windows)
    for (int u = tid; u < 1568; u += TB) {      // u = c*196 + wy*14 + wx
        int c = u / 196, rem = u - c * 196;
        int wy = rem / 14, wx = rem - wy * 14;
        int p0 = wy * 56 + wx * 2;
        int sh = c * 4;
        int m0 = (t2n[p0] >> sh) & 15;
        int m1 = (t2n[p0 + 1] >> sh) & 15;
        int m2 = (t2n[p0 + HW] >> sh) & 15;
        int m3 = (t2n[p0 + HW + 1] >> sh) & 15;
        int tqv = min(min(m0, m1), min(m2, m3));
        tqA[u] = (unsigned char)tqv;
        if (tqv < 8) atomicAdd(&bcnt[tqv], 1);
    }
    __syncthreads();
    if (tid == 0) {
        int s = 0;
#pragma unroll
        for (int t = 0; t < TT; t++) { bofs[t] = s; s += bcnt[t]; }
        bofs[8] = s;
    }
    __syncthreads();
    if (tid < 8) bput[tid] = bofs[tid];
    __syncthreads();
    for (int u = tid; u < 1568; u += TB) {
        int tqv = tqA[u];
        if (tqv < 8) {
            int j = atomicAdd(&bput[tqv], 1);
            int c = u / 196, rem = u - c * 196;
            slist[j] = (unsigned short)((co0 + c) * 196 + rem);
        }
    }

    // ---- wait for wT slices (long since done)
    if (tid < 98) {
        while (__hip_atomic_load(&tflags[tid], __ATOMIC_ACQUIRE,
                                 __HIP_MEMORY_SCOPE_AGENT) != MAGIC)
            __builtin_amdgcn_s_sleep(2);
    }
    __syncthreads();                            // wc/mask/t2n dead -> prefix reuse

    // ---- FC1 sorted-prefix scan: 8 single-wave streams, unroll-4 loads
    {
        const int lane = tid & 63;
        const int w = tid >> 6;
        const float* wA = wT + lane;
        const float* wB = wT + 64 + lane;
        float acc0 = 0.f, acc1 = 0.f;
#pragma unroll 1
        for (int t = 0; t < TT; t++) {
            const int lo = bofs[t];
            const int n = bofs[t + 1] - lo;
            int j = w;
            for (; j + 24 < n; j += 32) {
                int u0 = (int)slist[lo + j] * 100;
                int u1 = (int)slist[lo + j + 8] * 100;
                int u2 = (int)slist[lo + j + 16] * 100;
                int u3 = (int)slist[lo + j + 24] * 100;
                float a0 = wA[u0], a1 = wA[u1], a2 = wA[u2], a3 = wA[u3];
                if (lane < 36) {
                    float b0 = wB[u0], b1 = wB[u1], b2 = wB[u2], b3 = wB[u3];
                    acc1 += b0; acc1 += b1; acc1 += b2; acc1 += b3;
                }
                acc0 += a0; acc0 += a1; acc0 += a2; acc0 += a3;
            }
            for (; j < n; j += 8) {
                int u0 = (int)slist[lo + j] * 100;
                acc0 += wA[u0];
                if (lane < 36) acc1 += wB[u0];
            }
            prefixLDS[(w * TT + t) * NFC + lane] = acc0;
            if (lane < 36) prefixLDS[(w * TT + t) * NFC + 64 + lane] = acc1;
        }
    }
    __syncthreads();

    // ---- store half-prefix (CUMULATIVE at t) to private global region
    if (tid < NFC) {
#pragma unroll
        for (int t = 0; t < TT; t++) {
            float s = 0.f;
#pragma unroll
            for (int w = 0; w < 8; w++) s += prefixLDS[(w * TT + t) * NFC + tid];
            vfcb[(((size_t)b * 2 + half) * TT + t) * NFC + tid] = s;
        }
    }

    // ---- fr_ready gate, flush hist1/2
    if (tid == 0) {
        while (__hip_atomic_load(fr_ready, __ATOMIC_ACQUIRE,
                                 __HIP_MEMORY_SCOPE_AGENT) != MAGIC)
            __builtin_amdgcn_s_sleep(2);
    }
    __syncthreads();
    if (tid < 16) {
        int h = hist[tid];
        if (h) GLB_ADD(&fr_g[(tid & 7) * 4 + (tid >> 3)], (float)h);
    }
}

// ---------------------------------------------------------------------------
// Per-image tail: t3 from the two halves' CUMULATIVE prefixes (assignment,
// not accumulation — R11 bug), FC2 buckets, readout IF, latency score;
// 512th-done block computes reg_loss (fused finalize).
__global__ void snn_d(const float* __restrict__ vfcb, const float* __restrict__ w_fc2,
                      float* __restrict__ out, unsigned int* __restrict__ ctrl)
{
    __shared__ unsigned char t3L[NFC];
    __shared__ int hist3[TT], hist4[TT];
    __shared__ int lastflag;
    float* fr_g = (float*)(ctrl + 98);
    unsigned int* done2 = ctrl + 130;
    const int tid = threadIdx.x;
    const int b = blockIdx.x;
    if (tid < TT) { hist3[tid] = 0; hist4[tid] = 0; }
    __syncthreads();
    if (tid < NFC) {
        int t3 = 8;
#pragma unroll
        for (int t = 0; t < TT; t++) {
            float v = vfcb[(((size_t)b * 2 + 0) * TT + t) * NFC + tid]
                    + vfcb[(((size_t)b * 2 + 1) * TT + t) * NFC + tid];
            if (t3 == 8 && v >= 1.0f) t3 = t;
        }
        t3L[tid] = (unsigned char)t3;
        if (t3 < 8) atomicAdd(&hist3[t3], 1);
    }
    __syncthreads();
    if (tid < NOUT) {
        float acc8[TT] = {0.f, 0.f, 0.f, 0.f, 0.f, 0.f, 0.f, 0.f};
        for (int i = 0; i < NFC; i++) {
            float w = w_fc2[tid * NFC + i];
            int tv = t3L[i];
#pragma unroll
            for (int k = 0; k < TT; k++) acc8[k] += (tv == k) ? w : 0.f;
        }
        float vout = 0.f; int cnt = 0; float lat = 0.f;
#pragma unroll
        for (int t = 0; t < TT; t++) {
            vout += acc8[t];
            if (vout >= 1.0f) { vout = 0.f; cnt++; atomicAdd(&hist4[t], 1); }
            if (cnt >= 1) lat += 1.f;
        }
        out[b * NOUT + tid] = lat * 0.125f;
    }
    __syncthreads();
    if (tid < TT) {
        if (hist3[tid]) GLB_ADD(&fr_g[tid * 4 + 2], (float)hist3[tid]);
        if (hist4[tid]) GLB_ADD(&fr_g[tid * 4 + 3], (float)hist4[tid]);
    }
    __syncthreads();
    if (tid == 0) {
        unsigned int old = __hip_atomic_fetch_add(done2, 1u, __ATOMIC_ACQ_REL,
                                                  __HIP_MEMORY_SCOPE_AGENT);
        lastflag = (old == (unsigned)(NIMG - 1));
    }
    __syncthreads();
    if (lastflag && tid == 0) {
        const float inv0 = 1.f / 6422528.f;     // B*16*28*28
        const float inv2 = 1.f / 51200.f;       // B*100
        const float inv3 = 1.f / 5120.f;        // B*10
        const float invs[4] = { inv0, inv0, inv2, inv3 };
        float reg = 0.f;
        for (int l = 0; l < 4; l++) {
            float mx = -INFINITY;
            for (int t = 0; t < TT; t++) {
                float v = __hip_atomic_load(&fr_g[t * 4 + l], __ATOMIC_RELAXED,
                                            __HIP_MEMORY_SCOPE_AGENT);
                mx = fmaxf(mx, v * invs[l]);
            }
            reg += mx;
        }
        out[NIMG * NOUT] = reg;
    }
}

// ---------------------------------------------------------------------------
extern "C" void kernel_launch(void* const* d_in, const int* in_sizes, int n_in,
                              void* d_out, int out_size, void* d_ws, size_t ws_size,
                              hipStream_t stream) {
    const float* x       = (const float*)d_in[0];
    const float* w_sconv = (const float*)d_in[1];
    const float* w_conv  = (const float*)d_in[2];
    const float* w_fc1   = (const float*)d_in[3];
    const float* w_fc2   = (const float*)d_in[4];
    float* out = (float*)d_out;

    float* wT          = (float*)d_ws;
    float* vfcb        = wT + WT_FLOATS;
    unsigned int* ctrl = (unsigned int*)(vfcb + VFCB_FLOATS);

    snn_main<<<NIMG * 2, TB, 0, stream>>>(x, w_sconv, w_conv, w_fc1, w_fc2,
                                          wT, vfcb, out, ctrl);
    snn_d<<<NIMG, 128, 0, stream>>>(vfcb, w_fc2, out, ctrl);
}